// Round 1
// baseline (487.732 us; speedup 1.0000x reference)
//
#include <hip/hip_runtime.h>

// ---------------------------------------------------------------------------
// CVX_Reasoning_Engine: z(16384x512) ++ bounds -> 516 ->512->256->128->64->256
// lrelu(0.2) on layers 1-4; layer 5 + closed-form QP epilogue fused.
// Round 1: correct fp32 baseline. 4x tiled GEMM + fused final kernel.
// ---------------------------------------------------------------------------

#define MROWS 16384
#define TM 64
#define TN 64
#define TK 16

// C[M,N] = lrelu(A[M,K] @ W[K,N] + bias), A = [Amain(lda cols) | extra bcast]
__global__ __launch_bounds__(256) void gemm_lrelu(
    const float* __restrict__ A, int lda,
    const float* __restrict__ extra,          // broadcast columns (or nullptr)
    const float* __restrict__ W,              // K x N row-major
    const float* __restrict__ bias,           // N
    float* __restrict__ C,                    // M x N
    int N, int K)
{
    __shared__ __align__(16) float As[TK][TM];   // [k][m]
    __shared__ __align__(16) float Bs[TK][TN];   // [k][n]

    const int bm = blockIdx.y * TM;
    const int bn = blockIdx.x * TN;
    const int tid = threadIdx.x;
    const int tx = tid & 15;          // 16x16 thread grid, 4x4 micro-tile
    const int ty = tid >> 4;

    float acc[4][4] = {};

    for (int kt = 0; kt < K; kt += TK) {
        // --- A tile: 64 rows x 16 k. thread t: row m=t>>2, k block (t&3)*4
        {
            const int m  = tid >> 2;
            const int kq = (tid & 3) * 4;
            const size_t rowbase = (size_t)(bm + m) * lda;
            #pragma unroll
            for (int i = 0; i < 4; ++i) {
                const int gk = kt + kq + i;
                float v = 0.f;
                if (gk < K) v = (gk < lda) ? A[rowbase + gk] : extra[gk - lda];
                As[kq + i][m] = v;
            }
        }
        // --- B tile: 16 k x 64 n. thread t: n=t&63, k block (t>>6)*4
        {
            const int n  = tid & 63;
            const int k0 = (tid >> 6) * 4;
            #pragma unroll
            for (int i = 0; i < 4; ++i) {
                const int gk = kt + k0 + i;
                Bs[k0 + i][n] = (gk < K) ? W[(size_t)gk * N + bn + n] : 0.f;
            }
        }
        __syncthreads();

        #pragma unroll
        for (int k = 0; k < TK; ++k) {
            const float4 a4 = ((const float4*)&As[k][0])[ty];
            const float4 b4 = ((const float4*)&Bs[k][0])[tx];
            const float a[4] = {a4.x, a4.y, a4.z, a4.w};
            const float b[4] = {b4.x, b4.y, b4.z, b4.w};
            #pragma unroll
            for (int i = 0; i < 4; ++i)
                #pragma unroll
                for (int j = 0; j < 4; ++j)
                    acc[i][j] = fmaf(a[i], b[j], acc[i][j]);
        }
        __syncthreads();
    }

    // epilogue: bias + lrelu, float4 stores
    #pragma unroll
    for (int i = 0; i < 4; ++i) {
        const int gm = bm + ty * 4 + i;
        const int gn = bn + tx * 4;
        float4 o;
        float* op = &o.x;
        #pragma unroll
        for (int j = 0; j < 4; ++j) {
            float v = acc[i][j] + bias[gn + j];
            op[j] = v > 0.f ? v : 0.2f * v;
        }
        ((float4*)&C[(size_t)gm * N + gn])[0] = o;
    }
}

// Layer 5 (K=64 -> N=256) + QP epilogue. One wave per batch row; lane = object.
__global__ __launch_bounds__(256) void final_qp(
    const float* __restrict__ h4,     // M x 64
    const float* __restrict__ W5,     // 64 x 256 row-major
    const float* __restrict__ c5,     // 256
    const float* __restrict__ bounds, // 4
    float* __restrict__ out)          // M x 64 x 4
{
    const int row  = (blockIdx.x * blockDim.x + threadIdx.x) >> 6;
    const int lane = threadIdx.x & 63;

    const float hv = h4[(size_t)row * 64 + lane];

    const float4* __restrict__ W5v = (const float4*)W5;  // [k][64] of float4
    const float4 cc = ((const float4*)c5)[lane];
    float px = cc.x, py = cc.y, pw = cc.z, ph = cc.w;

    #pragma unroll
    for (int k = 0; k < 64; ++k) {
        const float a = __shfl(hv, k, 64);
        const float4 w = W5v[k * 64 + lane];
        px = fmaf(a, w.x, px);
        py = fmaf(a, w.y, py);
        pw = fmaf(a, w.z, pw);
        ph = fmaf(a, w.w, ph);
    }

    const float b0 = bounds[0], b1 = bounds[1], b2 = bounds[2], b3 = bounds[3];

    // axis solve: min (x-pp)^2+(g-pg)^2 s.t. x>=lo, g>=1, x+g<=hi
    float xs, wo, ys, ho;
    {
        const float pp = px, pg = pw, lo = b0, hi = b2;
        const float x0 = fmaxf(pp, lo);
        const float g0 = fmaxf(pg, 1.0f);
        const float t  = 0.5f * (hi - pp - pg);
        const float xl = fminf(fmaxf(pp + t, lo), hi - 1.0f);
        const bool over = (x0 + g0) > hi;
        const float x = over ? xl : x0;
        const float g = over ? (hi - xl) : g0;
        xs = x; wo = x + g;
    }
    {
        const float pp = py, pg = ph, lo = b1, hi = b3;
        const float x0 = fmaxf(pp, lo);
        const float g0 = fmaxf(pg, 1.0f);
        const float t  = 0.5f * (hi - pp - pg);
        const float xl = fminf(fmaxf(pp + t, lo), hi - 1.0f);
        const bool over = (x0 + g0) > hi;
        const float x = over ? xl : x0;
        const float g = over ? (hi - xl) : g0;
        ys = x; ho = x + g;
    }

    float4 o;
    o.x = xs; o.y = ys; o.z = wo; o.w = ho;
    ((float4*)out)[(size_t)row * 64 + lane] = o;
}

extern "C" void kernel_launch(void* const* d_in, const int* in_sizes, int n_in,
                              void* d_out, int out_size, void* d_ws, size_t ws_size,
                              hipStream_t stream) {
    const float* z      = (const float*)d_in[0];
    const float* bounds = (const float*)d_in[1];
    const float* W1 = (const float*)d_in[2];
    const float* c1 = (const float*)d_in[3];
    const float* W2 = (const float*)d_in[4];
    const float* c2 = (const float*)d_in[5];
    const float* W3 = (const float*)d_in[6];
    const float* c3 = (const float*)d_in[7];
    const float* W4 = (const float*)d_in[8];
    const float* c4 = (const float*)d_in[9];
    const float* W5 = (const float*)d_in[10];
    const float* c5 = (const float*)d_in[11];
    float* out = (float*)d_out;

    // workspace ping-pong: bufA holds up to 16384x512, bufB up to 16384x256
    float* bufA = (float*)d_ws;                 // 8,388,608 floats (32 MB)
    float* bufB = bufA + (size_t)MROWS * 512;   // 4,194,304 floats (16 MB)
    float* h1 = bufA;   // 16384 x 512
    float* h2 = bufB;   // 16384 x 256
    float* h3 = bufA;   // 16384 x 128 (h1 dead)
    float* h4 = bufB;   // 16384 x  64 (h2 dead)

    const dim3 blk(256);
    // layer 1: A = [z | bounds], K=516
    gemm_lrelu<<<dim3(512 / TN, MROWS / TM), blk, 0, stream>>>(
        z, 512, bounds, W1, c1, h1, 512, 516);
    // layer 2: 512 -> 256
    gemm_lrelu<<<dim3(256 / TN, MROWS / TM), blk, 0, stream>>>(
        h1, 512, nullptr, W2, c2, h2, 256, 512);
    // layer 3: 256 -> 128
    gemm_lrelu<<<dim3(128 / TN, MROWS / TM), blk, 0, stream>>>(
        h2, 256, nullptr, W3, c3, h3, 128, 256);
    // layer 4: 128 -> 64
    gemm_lrelu<<<dim3(64 / TN, MROWS / TM), blk, 0, stream>>>(
        h3, 128, nullptr, W4, c4, h4, 64, 128);
    // layer 5 + QP epilogue: one wave per row
    final_qp<<<dim3(MROWS / 4), blk, 0, stream>>>(h4, W5, c5, bounds, out);
}

// Round 2
// 225.318 us; speedup vs baseline: 2.1646x; 2.1646x over previous
//
#include <hip/hip_runtime.h>

// ---------------------------------------------------------------------------
// CVX_Reasoning_Engine — Round 2: bf16 MFMA for layers 1-4.
//   pack_a1: [z | bounds | 0] -> bf16 16384x544
//   pack_wt: W_i (KxN fp32) -> Wt_i (N x Kpad bf16, transposed, zero-padded)
//   gemm_mfma_lrelu: C = lrelu(A@Wt^T + bias), 16x16x32 bf16 MFMA, fp32 acc
//   final_qp: layer 5 (K=64) via wave shuffle + closed-form QP, fp32 out
// ---------------------------------------------------------------------------

#define MROWS 16384

typedef __attribute__((ext_vector_type(8))) short bf16x8;   // 8 bf16 = 4 VGPRs
typedef __attribute__((ext_vector_type(4))) float floatx4;

__device__ __forceinline__ unsigned short f2bf(float x) {
    union { float f; unsigned u; } c; c.f = x;
    unsigned r = c.u + 0x7fffu + ((c.u >> 16) & 1u);   // RNE
    return (unsigned short)(r >> 16);
}
__device__ __forceinline__ float bf2f(unsigned short b) {
    union { unsigned u; float f; } c; c.u = ((unsigned)b) << 16;
    return c.f;
}

// ---- pack z ++ bounds -> bf16, K padded 516 -> 544 -------------------------
__global__ __launch_bounds__(256) void pack_a1(
    const float* __restrict__ z, const float* __restrict__ bounds,
    unsigned short* __restrict__ A1)
{
    const int row = blockIdx.y;
    const int k = blockIdx.x * 256 + threadIdx.x;
    if (k >= 544) return;
    float v;
    if (k < 512)      v = z[(size_t)row * 512 + k];
    else if (k < 516) v = bounds[k - 512];
    else              v = 0.f;
    A1[(size_t)row * 544 + k] = f2bf(v);
}

// ---- transpose+pad all 4 weight matrices into bf16 Wt[n][kpad] -------------
__global__ __launch_bounds__(256) void pack_wt(
    const float* __restrict__ W1, unsigned short* __restrict__ T1,
    const float* __restrict__ W2, unsigned short* __restrict__ T2,
    const float* __restrict__ W3, unsigned short* __restrict__ T3,
    const float* __restrict__ W4, unsigned short* __restrict__ T4)
{
    const float* W; unsigned short* T; int K, N, Kp;
    switch (blockIdx.y) {
        case 0:  W = W1; T = T1; K = 516; N = 512; Kp = 544; break;
        case 1:  W = W2; T = T2; K = 512; N = 256; Kp = 512; break;
        case 2:  W = W3; T = T3; K = 256; N = 128; Kp = 256; break;
        default: W = W4; T = T4; K = 128; N = 64;  Kp = 128; break;
    }
    const int idx = blockIdx.x * 256 + threadIdx.x;
    if (idx >= N * Kp) return;
    const int n = idx / Kp, k = idx - n * Kp;
    T[idx] = (k < K) ? f2bf(W[(size_t)k * N + n]) : (unsigned short)0;
}

// ---- bf16 MFMA GEMM: C[M,N] = lrelu(A[M,K] @ Wt[N,K]^T + bias) -------------
// Wave tile 64x64 (4x4 fragments of 16x16x32). Block = WR x WC waves.
template<int BM, int BN, int WR, int WC>
__global__ __launch_bounds__(WR * WC * 64) void gemm_mfma_lrelu(
    const unsigned short* __restrict__ A, int strideA,  // M x K bf16
    const unsigned short* __restrict__ Wt,              // N x K bf16 (transposed)
    const float* __restrict__ bias,                     // N fp32
    unsigned short* __restrict__ C,                     // M x N bf16
    int N, int K)                                       // K multiple of 32
{
    constexpr int BLOCK = WR * WC * 64;
    constexpr int LDK = 40;                             // 80 B row: 20-bank stride
    __shared__ unsigned short As[BM * LDK];
    __shared__ unsigned short Bs[BN * LDK];

    const int tid  = threadIdx.x;
    const int wid  = tid >> 6;
    const int lane = tid & 63;
    const int wm = wid / WC, wn = wid % WC;
    const int m_l = lane & 15, quad = lane >> 4;
    const int bm = blockIdx.y * BM;
    const int bn = blockIdx.x * BN;

    floatx4 acc[4][4];
    #pragma unroll
    for (int i = 0; i < 4; ++i)
        #pragma unroll
        for (int j = 0; j < 4; ++j)
            acc[i][j] = (floatx4){0.f, 0.f, 0.f, 0.f};

    for (int kt = 0; kt < K; kt += 32) {
        // stage A tile: BM rows x 32 k, 16 B chunks
        #pragma unroll 2
        for (int t = tid; t < BM * 4; t += BLOCK) {
            const int row = t >> 2, kc = (t & 3) * 8;
            const uint4 v = *(const uint4*)(A + (size_t)(bm + row) * strideA + kt + kc);
            *(uint4*)(&As[row * LDK + kc]) = v;
        }
        // stage B tile (Wt rows are n): BN rows x 32 k
        #pragma unroll 2
        for (int t = tid; t < BN * 4; t += BLOCK) {
            const int row = t >> 2, kc = (t & 3) * 8;
            const uint4 v = *(const uint4*)(Wt + (size_t)(bn + row) * K + kt + kc);
            *(uint4*)(&Bs[row * LDK + kc]) = v;
        }
        __syncthreads();

        bf16x8 af[4], bfr[4];
        #pragma unroll
        for (int i = 0; i < 4; ++i) {
            af[i]  = *(const bf16x8*)(&As[(wm * 64 + i * 16 + m_l) * LDK + quad * 8]);
            bfr[i] = *(const bf16x8*)(&Bs[(wn * 64 + i * 16 + m_l) * LDK + quad * 8]);
        }
        #pragma unroll
        for (int i = 0; i < 4; ++i)
            #pragma unroll
            for (int j = 0; j < 4; ++j)
                acc[i][j] = __builtin_amdgcn_mfma_f32_16x16x32_bf16(
                                af[i], bfr[j], acc[i][j], 0, 0, 0);
        __syncthreads();
    }

    // epilogue: bias + lrelu -> bf16. C/D layout: col = lane&15, row = quad*4+reg
    #pragma unroll
    for (int j = 0; j < 4; ++j) {
        const int col = bn + wn * 64 + j * 16 + m_l;
        const float bv = bias[col];
        #pragma unroll
        for (int i = 0; i < 4; ++i) {
            const int row0 = bm + wm * 64 + i * 16 + quad * 4;
            #pragma unroll
            for (int r = 0; r < 4; ++r) {
                float v = acc[i][j][r] + bv;
                v = v > 0.f ? v : 0.2f * v;
                C[(size_t)(row0 + r) * N + col] = f2bf(v);
            }
        }
    }
}

// ---- layer 5 (64 -> 256) + QP epilogue; one wave per batch row --------------
__global__ __launch_bounds__(256) void final_qp(
    const unsigned short* __restrict__ h4,  // M x 64 bf16
    const float* __restrict__ W5,           // 64 x 256 fp32 row-major
    const float* __restrict__ c5,           // 256
    const float* __restrict__ bounds,       // 4
    float* __restrict__ out)                // M x 64 x 4 fp32
{
    const int row  = (blockIdx.x * blockDim.x + threadIdx.x) >> 6;
    const int lane = threadIdx.x & 63;

    const float hv = bf2f(h4[(size_t)row * 64 + lane]);

    const float4* __restrict__ W5v = (const float4*)W5;  // [k][64 objs] of float4
    const float4 cc = ((const float4*)c5)[lane];
    float px = cc.x, py = cc.y, pw = cc.z, ph = cc.w;

    #pragma unroll
    for (int k = 0; k < 64; ++k) {
        const float a = __shfl(hv, k, 64);
        const float4 w = W5v[k * 64 + lane];
        px = fmaf(a, w.x, px);
        py = fmaf(a, w.y, py);
        pw = fmaf(a, w.z, pw);
        ph = fmaf(a, w.w, ph);
    }

    const float b0 = bounds[0], b1 = bounds[1], b2 = bounds[2], b3 = bounds[3];
    float xs, wo, ys, ho;
    {
        const float x0 = fmaxf(px, b0);
        const float g0 = fmaxf(pw, 1.0f);
        const float t  = 0.5f * (b2 - px - pw);
        const float xl = fminf(fmaxf(px + t, b0), b2 - 1.0f);
        const bool over = (x0 + g0) > b2;
        const float x = over ? xl : x0;
        const float g = over ? (b2 - xl) : g0;
        xs = x; wo = x + g;
    }
    {
        const float x0 = fmaxf(py, b1);
        const float g0 = fmaxf(ph, 1.0f);
        const float t  = 0.5f * (b3 - py - ph);
        const float xl = fminf(fmaxf(py + t, b1), b3 - 1.0f);
        const bool over = (x0 + g0) > b3;
        const float x = over ? xl : x0;
        const float g = over ? (b3 - xl) : g0;
        ys = x; ho = x + g;
    }

    float4 o; o.x = xs; o.y = ys; o.z = wo; o.w = ho;
    ((float4*)out)[(size_t)row * 64 + lane] = o;
}

extern "C" void kernel_launch(void* const* d_in, const int* in_sizes, int n_in,
                              void* d_out, int out_size, void* d_ws, size_t ws_size,
                              hipStream_t stream) {
    const float* z      = (const float*)d_in[0];
    const float* bounds = (const float*)d_in[1];
    const float* W1 = (const float*)d_in[2];
    const float* c1 = (const float*)d_in[3];
    const float* W2 = (const float*)d_in[4];
    const float* c2 = (const float*)d_in[5];
    const float* W3 = (const float*)d_in[6];
    const float* c3 = (const float*)d_in[7];
    const float* W4 = (const float*)d_in[8];
    const float* c4 = (const float*)d_in[9];
    const float* W5 = (const float*)d_in[10];
    const float* c5 = (const float*)d_in[11];
    float* out = (float*)d_out;

    // ---- workspace layout (ushort elems; all offsets 16B-aligned) ----------
    unsigned short* ws = (unsigned short*)d_ws;
    unsigned short* A1  = ws;                         // 16384x544 = 8,912,896
    unsigned short* h3  = ws;                         // overlay (A1 dead): 16384x128
    unsigned short* h4  = ws + 2097152;               // overlay: 16384x64
    unsigned short* Wt1 = ws + 8912896;               // 512x544
    unsigned short* Wt2 = Wt1 + 278528;               // 256x512
    unsigned short* Wt3 = Wt2 + 131072;               // 128x256
    unsigned short* Wt4 = Wt3 + 32768;                // 64x128
    unsigned short* h1  = Wt4 + 8192;                 // 16384x512
    unsigned short* h2  = h1 + 8388608;               // 16384x256
    // total ≈ 43.9 MB < 48 MB ws

    // ---- packs -------------------------------------------------------------
    pack_a1<<<dim3(3, MROWS), 256, 0, stream>>>(z, bounds, A1);
    pack_wt<<<dim3(1088, 4), 256, 0, stream>>>(W1, Wt1, W2, Wt2, W3, Wt3, W4, Wt4);

    // ---- MFMA layers -------------------------------------------------------
    // L1: 544 -> 512
    gemm_mfma_lrelu<128,128,2,2><<<dim3(512/128, MROWS/128), 256, 0, stream>>>(
        A1, 544, Wt1, c1, h1, 512, 544);
    // L2: 512 -> 256
    gemm_mfma_lrelu<128,128,2,2><<<dim3(256/128, MROWS/128), 256, 0, stream>>>(
        h1, 512, Wt2, c2, h2, 256, 512);
    // L3: 256 -> 128
    gemm_mfma_lrelu<64,128,1,2><<<dim3(128/128, MROWS/64), 128, 0, stream>>>(
        h2, 256, Wt3, c3, h3, 128, 256);
    // L4: 128 -> 64
    gemm_mfma_lrelu<64,64,1,1><<<dim3(64/64, MROWS/64), 64, 0, stream>>>(
        h3, 128, Wt4, c4, h4, 64, 128);

    // ---- layer 5 + QP ------------------------------------------------------
    final_qp<<<dim3(MROWS/4), 256, 0, stream>>>(h4, W5, c5, bounds, out);
}

// Round 3
// 149.799 us; speedup vs baseline: 3.2559x; 1.5041x over previous
//
#include <hip/hip_runtime.h>

// ---------------------------------------------------------------------------
// CVX_Reasoning_Engine — Round 3: single fused kernel.
//   pack_wt: W_i (KxN fp32) -> Wt_i (N x Kp bf16, transposed, k-contiguous)
//   fused_mlp_qp: 512 blocks x 256 thr; 32 rows/block. Layer-1 input streamed
//   fp32->bf16 into LDS; h1..h4 ping-pong in LDS (never touch HBM); weights
//   read per-fragment from L2; layer-5 + closed-form QP fused at the tail.
// ---------------------------------------------------------------------------

#define MROWS 16384

typedef __attribute__((ext_vector_type(8))) short bf16x8;   // 8 bf16 = 4 VGPRs
typedef __attribute__((ext_vector_type(4))) float floatx4;

__device__ __forceinline__ unsigned short f2bf(float x) {
    union { float f; unsigned u; } c; c.f = x;
    unsigned r = c.u + 0x7fffu + ((c.u >> 16) & 1u);   // RNE
    return (unsigned short)(r >> 16);
}
__device__ __forceinline__ float bf2f(unsigned short b) {
    union { unsigned u; float f; } c; c.u = ((unsigned)b) << 16;
    return c.f;
}

// ---- transpose+pad all 4 weight matrices into bf16 Wt[n][kp] ---------------
__global__ __launch_bounds__(256) void pack_wt(
    const float* __restrict__ W1, unsigned short* __restrict__ T1,
    const float* __restrict__ W2, unsigned short* __restrict__ T2,
    const float* __restrict__ W3, unsigned short* __restrict__ T3,
    const float* __restrict__ W4, unsigned short* __restrict__ T4)
{
    const float* W; unsigned short* T; int K, N, Kp;
    switch (blockIdx.y) {
        case 0:  W = W1; T = T1; K = 516; N = 512; Kp = 544; break;
        case 1:  W = W2; T = T2; K = 512; N = 256; Kp = 512; break;
        case 2:  W = W3; T = T3; K = 256; N = 128; Kp = 256; break;
        default: W = W4; T = T4; K = 128; N = 64;  Kp = 128; break;
    }
    const int idx = blockIdx.x * 256 + threadIdx.x;
    if (idx >= N * Kp) return;
    const int n = idx / Kp, k = idx - n * Kp;
    T[idx] = (k < K) ? f2bf(W[(size_t)k * N + n]) : (unsigned short)0;
}

// ---- LDS layout (ushort element offsets) -----------------------------------
// R0: h1 (32x520)           [0,       16640)
// R1: misc = stage 2x32x72 | h2 32x264 | h4 32x72   [16640, 25088)
// R2: h3 (32x136)           [25088,   29440)        total 58,880 B
#define OFF_H1   0
#define OFF_MISC 16640
#define OFF_H3   25088
#define LDS_TOT  29440
#define LDA1S    72
#define LD_H1    520
#define LD_H2    264
#define LD_H3    136
#define LD_H4    72

// generic MFMA layer: C[32xN] = lrelu(A[32xK] @ Wt[N][Kp]^T + bias)
// 4 waves split N; wave tile 32 x (NF*16); fragments validated in R2.
template<int NF, int KSTEPS>
__device__ __forceinline__ void layer_gemm(
    unsigned short* lds, int offA, int lda, int offC, int ldc,
    const unsigned short* __restrict__ Wt, int Kp,
    const float* __restrict__ bias, int wid, int lane)
{
    const int m_l = lane & 15, quad = lane >> 4;
    const int colBase = wid * (NF * 16);
    floatx4 acc[2][NF];
    #pragma unroll
    for (int i = 0; i < 2; ++i)
        #pragma unroll
        for (int j = 0; j < NF; ++j)
            acc[i][j] = (floatx4){0.f, 0.f, 0.f, 0.f};

    #pragma unroll
    for (int ks = 0; ks < KSTEPS; ++ks) {
        const bf16x8 a0 = *(const bf16x8*)&lds[offA + (m_l     ) * lda + ks*32 + quad*8];
        const bf16x8 a1 = *(const bf16x8*)&lds[offA + (m_l + 16) * lda + ks*32 + quad*8];
        #pragma unroll
        for (int j = 0; j < NF; ++j) {
            const bf16x8 b = *(const bf16x8*)(Wt + (size_t)(colBase + j*16 + m_l) * Kp
                                                 + ks*32 + quad*8);
            acc[0][j] = __builtin_amdgcn_mfma_f32_16x16x32_bf16(a0, b, acc[0][j], 0, 0, 0);
            acc[1][j] = __builtin_amdgcn_mfma_f32_16x16x32_bf16(a1, b, acc[1][j], 0, 0, 0);
        }
    }
    // epilogue: bias + lrelu -> bf16 LDS. C/D: col=lane&15, row=quad*4+r.
    #pragma unroll
    for (int j = 0; j < NF; ++j) {
        const int col = colBase + j*16 + m_l;
        const float bv = bias[col];
        #pragma unroll
        for (int i = 0; i < 2; ++i)
            #pragma unroll
            for (int r = 0; r < 4; ++r) {
                float v = acc[i][j][r] + bv;
                v = v > 0.f ? v : 0.2f * v;
                lds[offC + (i*16 + quad*4 + r) * ldc + col] = f2bf(v);
            }
    }
}

__global__ __launch_bounds__(256, 2) void fused_mlp_qp(
    const float* __restrict__ z, const float* __restrict__ bounds,
    const unsigned short* __restrict__ Wt1, const float* __restrict__ c1,
    const unsigned short* __restrict__ Wt2, const float* __restrict__ c2,
    const unsigned short* __restrict__ Wt3, const float* __restrict__ c3,
    const unsigned short* __restrict__ Wt4, const float* __restrict__ c4,
    const float* __restrict__ W5, const float* __restrict__ c5,
    float* __restrict__ out)
{
    __shared__ unsigned short lds[LDS_TOT];
    const int tid  = threadIdx.x;
    const int wid  = tid >> 6, lane = tid & 63;
    const int m_l  = lane & 15, quad = lane >> 4;
    const int bm   = blockIdx.x * 32;

    // ---------------- Layer 1: K=544 streamed in 64-wide chunks -------------
    floatx4 acc1[2][8];
    #pragma unroll
    for (int i = 0; i < 2; ++i)
        #pragma unroll
        for (int j = 0; j < 8; ++j)
            acc1[i][j] = (floatx4){0.f, 0.f, 0.f, 0.f};

    const int srow = tid >> 3;          // 0..31
    const int skl  = (tid & 7) * 8;     // 0..56
    const float* __restrict__ zrow = z + (size_t)(bm + srow) * 512 + skl;

    // stage chunk 0 into buf0
    {
        const float4 p0 = *(const float4*)(zrow + 0);
        const float4 p1 = *(const float4*)(zrow + 4);
        unsigned short t[8] = {f2bf(p0.x), f2bf(p0.y), f2bf(p0.z), f2bf(p0.w),
                               f2bf(p1.x), f2bf(p1.y), f2bf(p1.z), f2bf(p1.w)};
        *(uint4*)&lds[OFF_MISC + srow * LDA1S + skl] = *(uint4*)t;
    }

    for (int c = 0; c < 8; ++c) {
        float4 q0 = {0.f,0.f,0.f,0.f}, q1 = {0.f,0.f,0.f,0.f};
        if (c + 1 < 8) {                       // prefetch next chunk (HBM in flight)
            q0 = *(const float4*)(zrow + (c + 1) * 64);
            q1 = *(const float4*)(zrow + (c + 1) * 64 + 4);
        }
        __syncthreads();                       // stage[buf c] ready
        const int off = OFF_MISC + (c & 1) * (32 * LDA1S);
        #pragma unroll
        for (int ks = 0; ks < 2; ++ks) {
            const bf16x8 a0 = *(const bf16x8*)&lds[off + (m_l     ) * LDA1S + ks*32 + quad*8];
            const bf16x8 a1 = *(const bf16x8*)&lds[off + (m_l + 16) * LDA1S + ks*32 + quad*8];
            #pragma unroll
            for (int j = 0; j < 8; ++j) {
                const int n = wid*128 + j*16 + m_l;
                const bf16x8 b = *(const bf16x8*)(Wt1 + (size_t)n * 544 + c*64 + ks*32 + quad*8);
                acc1[0][j] = __builtin_amdgcn_mfma_f32_16x16x32_bf16(a0, b, acc1[0][j], 0, 0, 0);
                acc1[1][j] = __builtin_amdgcn_mfma_f32_16x16x32_bf16(a1, b, acc1[1][j], 0, 0, 0);
            }
        }
        __syncthreads();                       // chunk c consumed
        if (c + 1 < 8) {
            unsigned short t[8] = {f2bf(q0.x), f2bf(q0.y), f2bf(q0.z), f2bf(q0.w),
                                   f2bf(q1.x), f2bf(q1.y), f2bf(q1.z), f2bf(q1.w)};
            *(uint4*)&lds[OFF_MISC + ((c + 1) & 1) * (32 * LDA1S) + srow * LDA1S + skl] = *(uint4*)t;
        } else {
            // chunk 8 (k 512..543): bounds then zeros -> buf0
            const int frow = tid >> 3;
            const int fkl  = (tid & 7) * 4;
            unsigned short t[4];
            #pragma unroll
            for (int i = 0; i < 4; ++i) {
                const int gk = 512 + fkl + i;
                t[i] = (gk < 516) ? f2bf(bounds[gk - 512]) : (unsigned short)0;
            }
            *(uint2*)&lds[OFF_MISC + frow * LDA1S + fkl] = *(uint2*)t;
        }
    }
    __syncthreads();
    // chunk 8: single k-step
    {
        const bf16x8 a0 = *(const bf16x8*)&lds[OFF_MISC + (m_l     ) * LDA1S + quad*8];
        const bf16x8 a1 = *(const bf16x8*)&lds[OFF_MISC + (m_l + 16) * LDA1S + quad*8];
        #pragma unroll
        for (int j = 0; j < 8; ++j) {
            const int n = wid*128 + j*16 + m_l;
            const bf16x8 b = *(const bf16x8*)(Wt1 + (size_t)n * 544 + 512 + quad*8);
            acc1[0][j] = __builtin_amdgcn_mfma_f32_16x16x32_bf16(a0, b, acc1[0][j], 0, 0, 0);
            acc1[1][j] = __builtin_amdgcn_mfma_f32_16x16x32_bf16(a1, b, acc1[1][j], 0, 0, 0);
        }
    }
    // L1 epilogue -> h1
    #pragma unroll
    for (int j = 0; j < 8; ++j) {
        const int col = wid*128 + j*16 + m_l;
        const float bv = c1[col];
        #pragma unroll
        for (int i = 0; i < 2; ++i)
            #pragma unroll
            for (int r = 0; r < 4; ++r) {
                float v = acc1[i][j][r] + bv;
                v = v > 0.f ? v : 0.2f * v;
                lds[OFF_H1 + (i*16 + quad*4 + r) * LD_H1 + col] = f2bf(v);
            }
    }
    __syncthreads();

    // ---------------- Layers 2-4 (LDS-resident) -----------------------------
    layer_gemm<4,16>(lds, OFF_H1,   LD_H1, OFF_MISC, LD_H2, Wt2, 512, c2, wid, lane);
    __syncthreads();
    layer_gemm<2,8 >(lds, OFF_MISC, LD_H2, OFF_H3,   LD_H3, Wt3, 256, c3, wid, lane);
    __syncthreads();
    layer_gemm<1,4 >(lds, OFF_H3,   LD_H3, OFF_MISC, LD_H4, Wt4, 128, c4, wid, lane);
    __syncthreads();

    // ---------------- Layer 5 (64->256 fp32) + QP ---------------------------
    const float4 cc = ((const float4*)c5)[lane];
    float ax[8], ay[8], aw[8], ah[8];
    #pragma unroll
    for (int r = 0; r < 8; ++r) { ax[r] = cc.x; ay[r] = cc.y; aw[r] = cc.z; ah[r] = cc.w; }
    const float4* __restrict__ W5v = (const float4*)W5;   // [k][64 objs]
    const int rbase = wid * 8;

    #pragma unroll 2
    for (int k4 = 0; k4 < 64; k4 += 4) {
        unsigned short hs[8][4];
        #pragma unroll
        for (int r = 0; r < 8; ++r) {
            const ushort4 t = *(const ushort4*)&lds[OFF_MISC + (rbase + r) * LD_H4 + k4];
            hs[r][0] = t.x; hs[r][1] = t.y; hs[r][2] = t.z; hs[r][3] = t.w;
        }
        #pragma unroll
        for (int kk = 0; kk < 4; ++kk) {
            const float4 w = W5v[(size_t)(k4 + kk) * 64 + lane];
            #pragma unroll
            for (int r = 0; r < 8; ++r) {
                const float h = bf2f(hs[r][kk]);
                ax[r] = fmaf(h, w.x, ax[r]);
                ay[r] = fmaf(h, w.y, ay[r]);
                aw[r] = fmaf(h, w.z, aw[r]);
                ah[r] = fmaf(h, w.w, ah[r]);
            }
        }
    }

    const float b0 = bounds[0], b1 = bounds[1], b2 = bounds[2], b3 = bounds[3];
    #pragma unroll
    for (int r = 0; r < 8; ++r) {
        float xs, wo, ys, ho;
        {
            const float px = ax[r], pw = aw[r];
            const float x0 = fmaxf(px, b0);
            const float g0 = fmaxf(pw, 1.0f);
            const float t  = 0.5f * (b2 - px - pw);
            const float xl = fminf(fmaxf(px + t, b0), b2 - 1.0f);
            const bool over = (x0 + g0) > b2;
            const float x = over ? xl : x0;
            const float g = over ? (b2 - xl) : g0;
            xs = x; wo = x + g;
        }
        {
            const float py = ay[r], ph = ah[r];
            const float x0 = fmaxf(py, b1);
            const float g0 = fmaxf(ph, 1.0f);
            const float t  = 0.5f * (b3 - py - ph);
            const float xl = fminf(fmaxf(py + t, b1), b3 - 1.0f);
            const bool over = (x0 + g0) > b3;
            const float x = over ? xl : x0;
            const float g = over ? (b3 - xl) : g0;
            ys = x; ho = x + g;
        }
        float4 o; o.x = xs; o.y = ys; o.z = wo; o.w = ho;
        ((float4*)out)[(size_t)(bm + rbase + r) * 64 + lane] = o;
    }
}

extern "C" void kernel_launch(void* const* d_in, const int* in_sizes, int n_in,
                              void* d_out, int out_size, void* d_ws, size_t ws_size,
                              hipStream_t stream) {
    const float* z      = (const float*)d_in[0];
    const float* bounds = (const float*)d_in[1];
    const float* W1 = (const float*)d_in[2];
    const float* c1 = (const float*)d_in[3];
    const float* W2 = (const float*)d_in[4];
    const float* c2 = (const float*)d_in[5];
    const float* W3 = (const float*)d_in[6];
    const float* c3 = (const float*)d_in[7];
    const float* W4 = (const float*)d_in[8];
    const float* c4 = (const float*)d_in[9];
    const float* W5 = (const float*)d_in[10];
    const float* c5 = (const float*)d_in[11];
    float* out = (float*)d_out;

    unsigned short* ws  = (unsigned short*)d_ws;
    unsigned short* Wt1 = ws;               // 512x544 = 278528
    unsigned short* Wt2 = Wt1 + 278528;     // 256x512 = 131072
    unsigned short* Wt3 = Wt2 + 131072;     // 128x256 = 32768
    unsigned short* Wt4 = Wt3 + 32768;      //  64x128 =  8192

    pack_wt<<<dim3(1088, 4), 256, 0, stream>>>(W1, Wt1, W2, Wt2, W3, Wt3, W4, Wt4);
    fused_mlp_qp<<<dim3(MROWS / 32), 256, 0, stream>>>(
        z, bounds, Wt1, c1, Wt2, c2, Wt3, c3, Wt4, c4, W5, c5, out);
}

// Round 4
// 137.271 us; speedup vs baseline: 3.5530x; 1.0913x over previous
//
#include <hip/hip_runtime.h>

// ---------------------------------------------------------------------------
// CVX_Reasoning_Engine — Round 4: fragment-order weight packing.
//   Weights pre-swizzled so each wave's MFMA B-fragment is one contiguous
//   1 KB burst (addr = base + lane*16B): kills the 16-way VMEM scatter that
//   made R3 latency-bound. h3 overlaid into dead h1 -> LDS 50.2 KB ->
//   3 blocks/CU. Numerics identical to R3 (absmax 0.03125).
// ---------------------------------------------------------------------------

#define MROWS 16384

typedef __attribute__((ext_vector_type(8))) short bf16x8;   // 8 bf16 = 4 VGPRs
typedef __attribute__((ext_vector_type(4))) float floatx4;

__device__ __forceinline__ unsigned short f2bf(float x) {
    union { float f; unsigned u; } c; c.f = x;
    unsigned r = c.u + 0x7fffu + ((c.u >> 16) & 1u);   // RNE
    return (unsigned short)(r >> 16);
}
__device__ __forceinline__ float bf2f(unsigned short b) {
    union { unsigned u; float f; } c; c.u = ((unsigned)b) << 16;
    return c.f;
}

// ---- pack W (KxN fp32) -> fragment-ordered bf16 ----------------------------
// T[((ntile*KS + ks)*64 + lane)*8 + e] = W[k][n],  n = ntile*16 + (lane&15),
// k = ks*32 + (lane>>4)*8 + e.  Reads coalesced (idx = k*N + n, n fastest).
__global__ __launch_bounds__(256) void pack_wt(
    const float* __restrict__ W1, unsigned short* __restrict__ T1,
    const float* __restrict__ W2, unsigned short* __restrict__ T2,
    const float* __restrict__ W3, unsigned short* __restrict__ T3,
    const float* __restrict__ W4, unsigned short* __restrict__ T4)
{
    const float* W; unsigned short* T; int Kreal, KS, nshift;
    switch (blockIdx.y) {
        case 0:  W = W1; T = T1; Kreal = 516; KS = 17; nshift = 9; break;
        case 1:  W = W2; T = T2; Kreal = 512; KS = 16; nshift = 8; break;
        case 2:  W = W3; T = T3; Kreal = 256; KS = 8;  nshift = 7; break;
        default: W = W4; T = T4; Kreal = 128; KS = 4;  nshift = 6; break;
    }
    const int N = 1 << nshift;
    const int idx = blockIdx.x * 256 + threadIdx.x;   // k*N + n over padded K
    if (idx >= N * KS * 32) return;
    const int k = idx >> nshift;
    const int n = idx & (N - 1);
    const unsigned short v = (k < Kreal) ? f2bf(W[idx]) : (unsigned short)0;
    const int ntile = n >> 4, m_l = n & 15;
    const int ks = k >> 5, quad = (k >> 3) & 3, e = k & 7;
    T[(size_t)(((ntile * KS + ks) * 64) + quad * 16 + m_l) * 8 + e] = v;
}

// ---- LDS layout (ushort element offsets) -----------------------------------
// h1 32x520 @0 ; misc = stage 2x32x72 | h2 32x264 | h4 32x72 @16640 ;
// h3 32x136 overlaid @0 (h1 dead when h3 live).  Total 50,176 B.
#define OFF_H1   0
#define OFF_MISC 16640
#define OFF_H3   0
#define LDS_TOT  25088
#define LDA1S    72
#define LD_H1    520
#define LD_H2    264
#define LD_H3    136
#define LD_H4    72

// generic MFMA layer: C[32xN] = lrelu(A[32xK] @ W^T + bias)
// Wt fragment-ordered; 4 waves split N; wave tile 32 x (NF*16).
template<int NF, int KSTEPS>
__device__ __forceinline__ void layer_gemm(
    unsigned short* lds, int offA, int lda, int offC, int ldc,
    const unsigned short* __restrict__ Wt,
    const float* __restrict__ bias, int wid, int lane)
{
    const int m_l = lane & 15, quad = lane >> 4;
    const unsigned short* __restrict__ Wl =
        Wt + ((size_t)(wid * NF) * KSTEPS * 64 + lane) * 8;
    floatx4 acc[2][NF];
    #pragma unroll
    for (int i = 0; i < 2; ++i)
        #pragma unroll
        for (int j = 0; j < NF; ++j)
            acc[i][j] = (floatx4){0.f, 0.f, 0.f, 0.f};

    #pragma unroll
    for (int ks = 0; ks < KSTEPS; ++ks) {
        const bf16x8 a0 = *(const bf16x8*)&lds[offA + (m_l     ) * lda + ks*32 + quad*8];
        const bf16x8 a1 = *(const bf16x8*)&lds[offA + (m_l + 16) * lda + ks*32 + quad*8];
        #pragma unroll
        for (int j = 0; j < NF; ++j) {
            const bf16x8 b = *(const bf16x8*)(Wl + (size_t)(j * KSTEPS + ks) * 512);
            acc[0][j] = __builtin_amdgcn_mfma_f32_16x16x32_bf16(a0, b, acc[0][j], 0, 0, 0);
            acc[1][j] = __builtin_amdgcn_mfma_f32_16x16x32_bf16(a1, b, acc[1][j], 0, 0, 0);
        }
    }
    // epilogue: bias + lrelu -> bf16 LDS. C/D: col=lane&15, row=quad*4+r.
    #pragma unroll
    for (int j = 0; j < NF; ++j) {
        const int col = wid * (NF * 16) + j * 16 + m_l;
        const float bv = bias[col];
        #pragma unroll
        for (int i = 0; i < 2; ++i)
            #pragma unroll
            for (int r = 0; r < 4; ++r) {
                float v = acc[i][j][r] + bv;
                v = v > 0.f ? v : 0.2f * v;
                lds[offC + (i*16 + quad*4 + r) * ldc + col] = f2bf(v);
            }
    }
}

__global__ __launch_bounds__(256, 3) void fused_mlp_qp(
    const float* __restrict__ z, const float* __restrict__ bounds,
    const unsigned short* __restrict__ Wt1, const float* __restrict__ c1,
    const unsigned short* __restrict__ Wt2, const float* __restrict__ c2,
    const unsigned short* __restrict__ Wt3, const float* __restrict__ c3,
    const unsigned short* __restrict__ Wt4, const float* __restrict__ c4,
    const float* __restrict__ W5, const float* __restrict__ c5,
    float* __restrict__ out)
{
    __shared__ unsigned short lds[LDS_TOT];
    const int tid  = threadIdx.x;
    const int wid  = tid >> 6, lane = tid & 63;
    const int m_l  = lane & 15, quad = lane >> 4;
    const int bm   = blockIdx.x * 32;

    // ---------------- Layer 1: K=544 streamed in 64-wide chunks -------------
    floatx4 acc1[2][8];
    #pragma unroll
    for (int i = 0; i < 2; ++i)
        #pragma unroll
        for (int j = 0; j < 8; ++j)
            acc1[i][j] = (floatx4){0.f, 0.f, 0.f, 0.f};

    const int srow = tid >> 3;          // 0..31
    const int skl  = (tid & 7) * 8;     // 0..56
    const float* __restrict__ zrow = z + (size_t)(bm + srow) * 512 + skl;
    // Wt1 fragment base for this wave (8 n-tiles, KS=17)
    const unsigned short* __restrict__ W1l = Wt1 + ((size_t)(wid * 8) * 17 * 64 + lane) * 8;

    // stage chunk 0 into buf0
    {
        const float4 p0 = *(const float4*)(zrow + 0);
        const float4 p1 = *(const float4*)(zrow + 4);
        unsigned short t[8] = {f2bf(p0.x), f2bf(p0.y), f2bf(p0.z), f2bf(p0.w),
                               f2bf(p1.x), f2bf(p1.y), f2bf(p1.z), f2bf(p1.w)};
        *(uint4*)&lds[OFF_MISC + srow * LDA1S + skl] = *(uint4*)t;
    }

    for (int c = 0; c < 8; ++c) {
        float4 q0 = {0.f,0.f,0.f,0.f}, q1 = {0.f,0.f,0.f,0.f};
        if (c + 1 < 8) {                       // prefetch next chunk (HBM in flight)
            q0 = *(const float4*)(zrow + (c + 1) * 64);
            q1 = *(const float4*)(zrow + (c + 1) * 64 + 4);
        }
        __syncthreads();                       // stage[buf c] ready
        const int off = OFF_MISC + (c & 1) * (32 * LDA1S);
        #pragma unroll
        for (int ks = 0; ks < 2; ++ks) {
            const bf16x8 a0 = *(const bf16x8*)&lds[off + (m_l     ) * LDA1S + ks*32 + quad*8];
            const bf16x8 a1 = *(const bf16x8*)&lds[off + (m_l + 16) * LDA1S + ks*32 + quad*8];
            #pragma unroll
            for (int j = 0; j < 8; ++j) {
                const bf16x8 b = *(const bf16x8*)(W1l + (size_t)(j * 17 + c*2 + ks) * 512);
                acc1[0][j] = __builtin_amdgcn_mfma_f32_16x16x32_bf16(a0, b, acc1[0][j], 0, 0, 0);
                acc1[1][j] = __builtin_amdgcn_mfma_f32_16x16x32_bf16(a1, b, acc1[1][j], 0, 0, 0);
            }
        }
        __syncthreads();                       // chunk c consumed
        if (c + 1 < 8) {
            unsigned short t[8] = {f2bf(q0.x), f2bf(q0.y), f2bf(q0.z), f2bf(q0.w),
                                   f2bf(q1.x), f2bf(q1.y), f2bf(q1.z), f2bf(q1.w)};
            *(uint4*)&lds[OFF_MISC + ((c + 1) & 1) * (32 * LDA1S) + srow * LDA1S + skl] = *(uint4*)t;
        } else {
            // chunk 8 (k 512..543): bounds then zeros -> buf0
            const int frow = tid >> 3;
            const int fkl  = (tid & 7) * 4;
            unsigned short t[4];
            #pragma unroll
            for (int i = 0; i < 4; ++i) {
                const int gk = 512 + fkl + i;
                t[i] = (gk < 516) ? f2bf(bounds[gk - 512]) : (unsigned short)0;
            }
            *(uint2*)&lds[OFF_MISC + frow * LDA1S + fkl] = *(uint2*)t;
        }
    }
    __syncthreads();
    // chunk 8: single k-step (ks index 16)
    {
        const bf16x8 a0 = *(const bf16x8*)&lds[OFF_MISC + (m_l     ) * LDA1S + quad*8];
        const bf16x8 a1 = *(const bf16x8*)&lds[OFF_MISC + (m_l + 16) * LDA1S + quad*8];
        #pragma unroll
        for (int j = 0; j < 8; ++j) {
            const bf16x8 b = *(const bf16x8*)(W1l + (size_t)(j * 17 + 16) * 512);
            acc1[0][j] = __builtin_amdgcn_mfma_f32_16x16x32_bf16(a0, b, acc1[0][j], 0, 0, 0);
            acc1[1][j] = __builtin_amdgcn_mfma_f32_16x16x32_bf16(a1, b, acc1[1][j], 0, 0, 0);
        }
    }
    // L1 epilogue -> h1
    #pragma unroll
    for (int j = 0; j < 8; ++j) {
        const int col = wid*128 + j*16 + m_l;
        const float bv = c1[col];
        #pragma unroll
        for (int i = 0; i < 2; ++i)
            #pragma unroll
            for (int r = 0; r < 4; ++r) {
                float v = acc1[i][j][r] + bv;
                v = v > 0.f ? v : 0.2f * v;
                lds[OFF_H1 + (i*16 + quad*4 + r) * LD_H1 + col] = f2bf(v);
            }
    }
    __syncthreads();

    // ---------------- Layers 2-4 (LDS-resident) -----------------------------
    layer_gemm<4,16>(lds, OFF_H1,   LD_H1, OFF_MISC, LD_H2, Wt2, c2, wid, lane);
    __syncthreads();
    layer_gemm<2,8 >(lds, OFF_MISC, LD_H2, OFF_H3,   LD_H3, Wt3, c3, wid, lane);
    __syncthreads();
    layer_gemm<1,4 >(lds, OFF_H3,   LD_H3, OFF_MISC, LD_H4, Wt4, c4, wid, lane);
    __syncthreads();

    // ---------------- Layer 5 (64->256 fp32) + QP ---------------------------
    const float4 cc = ((const float4*)c5)[lane];
    float ax[8], ay[8], aw[8], ah[8];
    #pragma unroll
    for (int r = 0; r < 8; ++r) { ax[r] = cc.x; ay[r] = cc.y; aw[r] = cc.z; ah[r] = cc.w; }
    const float4* __restrict__ W5v = (const float4*)W5;   // [k][64 objs]
    const int rbase = wid * 8;

    #pragma unroll 2
    for (int k4 = 0; k4 < 64; k4 += 4) {
        unsigned short hs[8][4];
        #pragma unroll
        for (int r = 0; r < 8; ++r) {
            const ushort4 t = *(const ushort4*)&lds[OFF_MISC + (rbase + r) * LD_H4 + k4];
            hs[r][0] = t.x; hs[r][1] = t.y; hs[r][2] = t.z; hs[r][3] = t.w;
        }
        #pragma unroll
        for (int kk = 0; kk < 4; ++kk) {
            const float4 w = W5v[(size_t)(k4 + kk) * 64 + lane];
            #pragma unroll
            for (int r = 0; r < 8; ++r) {
                const float h = bf2f(hs[r][kk]);
                ax[r] = fmaf(h, w.x, ax[r]);
                ay[r] = fmaf(h, w.y, ay[r]);
                aw[r] = fmaf(h, w.z, aw[r]);
                ah[r] = fmaf(h, w.w, ah[r]);
            }
        }
    }

    const float b0 = bounds[0], b1 = bounds[1], b2 = bounds[2], b3 = bounds[3];
    #pragma unroll
    for (int r = 0; r < 8; ++r) {
        float xs, wo, ys, ho;
        {
            const float px = ax[r], pw = aw[r];
            const float x0 = fmaxf(px, b0);
            const float g0 = fmaxf(pw, 1.0f);
            const float t  = 0.5f * (b2 - px - pw);
            const float xl = fminf(fmaxf(px + t, b0), b2 - 1.0f);
            const bool over = (x0 + g0) > b2;
            const float x = over ? xl : x0;
            const float g = over ? (b2 - xl) : g0;
            xs = x; wo = x + g;
        }
        {
            const float py = ay[r], ph = ah[r];
            const float x0 = fmaxf(py, b1);
            const float g0 = fmaxf(ph, 1.0f);
            const float t  = 0.5f * (b3 - py - ph);
            const float xl = fminf(fmaxf(py + t, b1), b3 - 1.0f);
            const bool over = (x0 + g0) > b3;
            const float x = over ? xl : x0;
            const float g = over ? (b3 - xl) : g0;
            ys = x; ho = x + g;
        }
        float4 o; o.x = xs; o.y = ys; o.z = wo; o.w = ho;
        ((float4*)out)[(size_t)(bm + rbase + r) * 64 + lane] = o;
    }
}

extern "C" void kernel_launch(void* const* d_in, const int* in_sizes, int n_in,
                              void* d_out, int out_size, void* d_ws, size_t ws_size,
                              hipStream_t stream) {
    const float* z      = (const float*)d_in[0];
    const float* bounds = (const float*)d_in[1];
    const float* W1 = (const float*)d_in[2];
    const float* c1 = (const float*)d_in[3];
    const float* W2 = (const float*)d_in[4];
    const float* c2 = (const float*)d_in[5];
    const float* W3 = (const float*)d_in[6];
    const float* c3 = (const float*)d_in[7];
    const float* W4 = (const float*)d_in[8];
    const float* c4 = (const float*)d_in[9];
    const float* W5 = (const float*)d_in[10];
    const float* c5 = (const float*)d_in[11];
    float* out = (float*)d_out;

    unsigned short* ws  = (unsigned short*)d_ws;
    unsigned short* Wt1 = ws;               // 512x544 = 278528
    unsigned short* Wt2 = Wt1 + 278528;     // 256x512 = 131072
    unsigned short* Wt3 = Wt2 + 131072;     // 128x256 = 32768
    unsigned short* Wt4 = Wt3 + 32768;      //  64x128 =  8192

    pack_wt<<<dim3(1088, 4), 256, 0, stream>>>(W1, Wt1, W2, Wt2, W3, Wt3, W4, Wt4);
    fused_mlp_qp<<<dim3(MROWS / 32), 256, 0, stream>>>(
        z, bounds, Wt1, c1, Wt2, c2, Wt3, c3, Wt4, c4, W5, c5, out);
}